// Round 9
// baseline (1446.828 us; speedup 1.0000x reference)
//
#include <hip/hip_runtime.h>
#include <hip/hip_bf16.h>

#define B_ 2048
#define N_ 8
#define D_ 1024
#define V_ 4096
#define LN_EPS_ 1e-5f

typedef __bf16 bf16x8 __attribute__((ext_vector_type(8)));
typedef float f32x4 __attribute__((ext_vector_type(4)));

#define GLB(p) ((const __attribute__((address_space(1))) void*)(p))
#define LDSP(p) ((__attribute__((address_space(3))) void*)(p))

static __device__ __forceinline__ unsigned short f2bf(float x) {
    union { float f; unsigned int u; } v;
    v.f = x;
    unsigned int r = v.u + 0x7fffu + ((v.u >> 16) & 1u);
    return (unsigned short)(r >> 16);
}

// ---------------------------------------------------------------------------
// prep: fused  (a) W_pred (N,D,V) f32 -> Wt (N,V,D) bf16   [blocks 2048..10239]
//              (b) gather+cumsum+LN+GELU -> H (N,B,D) bf16 [blocks 0..2047]
// ---------------------------------------------------------------------------
__global__ __launch_bounds__(256) void prep(const float* __restrict__ ie,
                                            const int* __restrict__ feats,
                                            const float* __restrict__ emb,
                                            const float* __restrict__ gamma,
                                            const float* __restrict__ beta,
                                            const float* __restrict__ W,
                                            unsigned short* __restrict__ H,
                                            unsigned short* __restrict__ Wt) {
    const int bid = blockIdx.x;
    const int t = threadIdx.x;

    if (bid >= 2048) {
        __shared__ unsigned short tile[64][65];
        const int w  = bid - 2048;
        const int v0 = (w & 63) * 64;
        const int d0 = ((w >> 6) & 15) * 64;
        const int n  = w >> 10;
        const int tx = t & 15, ty = t >> 4;
#pragma unroll
        for (int i = 0; i < 4; ++i) {
            const int d = ty + i * 16;
            const float4 w4 = *(const float4*)&W[((size_t)n * D_ + d0 + d) * V_ + v0 + tx * 4];
            tile[d][tx * 4 + 0] = f2bf(w4.x);
            tile[d][tx * 4 + 1] = f2bf(w4.y);
            tile[d][tx * 4 + 2] = f2bf(w4.z);
            tile[d][tx * 4 + 3] = f2bf(w4.w);
        }
        __syncthreads();
#pragma unroll
        for (int i = 0; i < 4; ++i) {
            const int v = ty + i * 16;
            ushort4 pk;
            pk.x = tile[tx * 4 + 0][v];
            pk.y = tile[tx * 4 + 1][v];
            pk.z = tile[tx * 4 + 2][v];
            pk.w = tile[tx * 4 + 3][v];
            *reinterpret_cast<ushort4*>(&Wt[((size_t)n * V_ + v0 + v) * D_ + d0 + tx * 4]) = pk;
        }
    } else {
        __shared__ float redS[4], redQ[4];
        const int b = bid;
        const int d0 = t * 4;
        const int lane = t & 63, wid = t >> 6;

        float4 s  = *(const float4*)&ie[(size_t)b * D_ + d0];
        const float4 g4 = *(const float4*)&gamma[d0];
        const float4 be4 = *(const float4*)&beta[d0];

        int fc[N_];
#pragma unroll
        for (int n = 0; n < N_; ++n) fc[n] = feats[b * N_ + n];

#pragma unroll
        for (int n = 0; n < N_; ++n) {
            float ls = s.x + s.y + s.z + s.w;
            float lq = s.x * s.x + s.y * s.y + s.z * s.z + s.w * s.w;
#pragma unroll
            for (int off = 32; off > 0; off >>= 1) {
                ls += __shfl_down(ls, off, 64);
                lq += __shfl_down(lq, off, 64);
            }
            if (lane == 0) { redS[wid] = ls; redQ[wid] = lq; }
            __syncthreads();
            const float tot  = redS[0] + redS[1] + redS[2] + redS[3];
            const float totq = redQ[0] + redQ[1] + redQ[2] + redQ[3];
            __syncthreads();

            const float mu   = tot * (1.0f / D_);
            const float var  = totq * (1.0f / D_) - mu * mu;
            const float rstd = rsqrtf(var + LN_EPS_);

            float h0 = (s.x - mu) * rstd * g4.x + be4.x;
            float h1 = (s.y - mu) * rstd * g4.y + be4.y;
            float h2 = (s.z - mu) * rstd * g4.z + be4.z;
            float h3 = (s.w - mu) * rstd * g4.w + be4.w;
            h0 = 0.5f * h0 * (1.0f + erff(h0 * 0.70710678f));
            h1 = 0.5f * h1 * (1.0f + erff(h1 * 0.70710678f));
            h2 = 0.5f * h2 * (1.0f + erff(h2 * 0.70710678f));
            h3 = 0.5f * h3 * (1.0f + erff(h3 * 0.70710678f));

            ushort4 pk;
            pk.x = f2bf(h0); pk.y = f2bf(h1); pk.z = f2bf(h2); pk.w = f2bf(h3);
            *reinterpret_cast<ushort4*>(&H[((size_t)n * B_ + b) * D_ + d0]) = pk;

            const float4 e = *(const float4*)&emb[((size_t)n * V_ + fc[n]) * (size_t)D_ + d0];
            s.x += e.x; s.y += e.y; s.z += e.z; s.w += e.w;
        }
    }
}

// ---------------------------------------------------------------------------
// gemm3: 256x256 tile, BK=32, 8 waves (2x4, wave-tile 128x64).
// TWO blocks per CU (LDS = 2 buffers x 32KB = 64KB): inter-block stall hiding
// (m114 co-scheduling) — when one block drains vmcnt/barrier, the other's
// waves issue MFMA. Per tile: vmcnt(0) [only own 4 loads outstanding; HBM
// latency covered by previous tile's compute] -> barrier -> 12 ds_read_b128 +
// stage t+1 -> 2x16 MFMA (setprio) -> barrier.
// Swizzle (R7-verified, 0 conflicts): phys 16B slot = logical ^ ((row>>1)&3),
// inverse pre-applied on the global source.
// ---------------------------------------------------------------------------
#define MF(a, b, c) __builtin_amdgcn_mfma_f32_16x16x32_bf16((a), (b), (c), 0, 0, 0)

#define STAGE2(KS, bb) { \
    __builtin_amdgcn_global_load_lds(GLB(Ab + (KS) + (size_t)(srow      ) * D_ + gsl), LDSP(lds + (bb) +         t * 16), 16, 0, 0); \
    __builtin_amdgcn_global_load_lds(GLB(Ab + (KS) + (size_t)(srow + 128) * D_ + gsl), LDSP(lds + (bb) +  8192 + t * 16), 16, 0, 0); \
    __builtin_amdgcn_global_load_lds(GLB(Bb + (KS) + (size_t)(srow      ) * D_ + gsl), LDSP(lds + (bb) + 16384 + t * 16), 16, 0, 0); \
    __builtin_amdgcn_global_load_lds(GLB(Bb + (KS) + (size_t)(srow + 128) * D_ + gsl), LDSP(lds + (bb) + 24576 + t * 16), 16, 0, 0); \
}

#define RD_A2(i, bb) (*(const bf16x8*)(lds + (bb) + ((i) * 32 + wr * 16 + lrow) * 64 + swk))
#define RD_B2(j, bb) (*(const bf16x8*)(lds + (bb) + 16384 + (wc * 64 + (j) * 16 + lrow) * 64 + swk))

#define TILE3(bc, bn, KS, DOSTG) { \
    asm volatile("s_waitcnt vmcnt(0)" ::: "memory"); \
    __builtin_amdgcn_s_barrier(); \
    bf16x8 Bf[4], Af[4]; \
    _Pragma("unroll") for (int j = 0; j < 4; ++j) Bf[j] = RD_B2(j, bc); \
    _Pragma("unroll") for (int i = 0; i < 4; ++i) Af[i] = RD_A2(i, bc); \
    if (DOSTG) { STAGE2(KS, bn); } \
    __builtin_amdgcn_s_setprio(1); \
    _Pragma("unroll") for (int i = 0; i < 4; ++i) \
        _Pragma("unroll") for (int j = 0; j < 4; ++j) \
            acc[i][j] = MF(Af[i], Bf[j], acc[i][j]); \
    __builtin_amdgcn_s_setprio(0); \
    _Pragma("unroll") for (int i = 0; i < 4; ++i) Af[i] = RD_A2((i) + 4, bc); \
    __builtin_amdgcn_s_setprio(1); \
    _Pragma("unroll") for (int i = 0; i < 4; ++i) \
        _Pragma("unroll") for (int j = 0; j < 4; ++j) \
            acc[i + 4][j] = MF(Af[i], Bf[j], acc[i + 4][j]); \
    __builtin_amdgcn_s_setprio(0); \
    __builtin_amdgcn_s_barrier(); \
}

__global__ __launch_bounds__(512, 4) void gemm3(const unsigned short* __restrict__ H,
                                                const unsigned short* __restrict__ Wt,
                                                const float* __restrict__ bp,
                                                float* __restrict__ out) {
    extern __shared__ char lds[];
    const int bid = blockIdx.x;
    // XCD chunking: XCD k (= bid&7) owns logical range [128k,128k+128) = one n
    const int logical = (bid & 7) * 128 + (bid >> 3);
    const int n  = logical >> 7;
    const int mt = (logical >> 4) & 7;
    const int vt = logical & 15;

    const int t = threadIdx.x;
    const int wid = t >> 6, lane = t & 63;
    const int wr = wid >> 2, wc = wid & 3;

    const unsigned short* Ab = H  + ((size_t)n * B_ + (size_t)mt * 256) * D_;
    const unsigned short* Bb = Wt + ((size_t)n * V_ + (size_t)vt * 256) * D_;

    const int srow = t >> 2;                              // 0..127
    const int gsl  = ((t & 3) ^ ((t >> 3) & 3)) * 8;      // inverse-swizzled source slot
    const int lrow = lane & 15;
    const int lkq  = lane >> 4;
    const int swk  = (lkq ^ ((lrow >> 1) & 3)) * 16;      // 2-way-free read swizzle
    const int col  = lane & 15;
    const int rg   = (lane >> 4) * 4;

    // bias (drained before pipeline)
    float bias[4];
#pragma unroll
    for (int j = 0; j < 4; ++j)
        bias[j] = bp[(size_t)n * V_ + vt * 256 + wc * 64 + j * 16 + col];
    asm volatile("s_waitcnt vmcnt(0)" ::: "memory");
    __builtin_amdgcn_sched_barrier(0);

    f32x4 acc[8][4] = {};

    // prologue: stage tile 0 into buf0
    STAGE2(0, 0);

#pragma unroll 1
    for (int it = 0; it < 15; ++it) {       // tiles 0..29, staging 1..30
        const int ks = it * 64 + 32;
        TILE3(0,     32768, ks,      1);    // compute 2it,   stage 2it+1
        TILE3(32768, 0,     ks + 32, 1);    // compute 2it+1, stage 2it+2
    }
    TILE3(0,     32768, 992, 1);            // tile 30, stages tile 31
    TILE3(32768, 0,     0,   0);            // tile 31 (no stage)

    // epilogue: C/D layout col = lane&15, row = (lane>>4)*4 + reg
    const int gc0 = vt * 256 + wc * 64 + col;
#pragma unroll
    for (int i = 0; i < 8; ++i) {
        const int row = mt * 256 + i * 32 + wr * 16 + rg;
#pragma unroll
        for (int j = 0; j < 4; ++j) {
            const int gcol = gc0 + j * 16;
#pragma unroll
            for (int r = 0; r < 4; ++r)
                out[((size_t)(row + r) * N_ + n) * V_ + gcol] = acc[i][j][r] + bias[j];
        }
    }
}

// ---------------------------------------------------------------------------
extern "C" void kernel_launch(void* const* d_in, const int* in_sizes, int n_in,
                              void* d_out, int out_size, void* d_ws, size_t ws_size,
                              hipStream_t stream) {
    const float* ie  = (const float*)d_in[0];
    const int*   fts = (const int*)d_in[1];
    const float* emb = (const float*)d_in[2];
    const float* W   = (const float*)d_in[3];
    const float* bp  = (const float*)d_in[4];
    const float* gam = (const float*)d_in[5];
    const float* bet = (const float*)d_in[6];
    float* out = (float*)d_out;

    unsigned short* Wt = (unsigned short*)d_ws;                                     // 64 MiB
    unsigned short* H  = (unsigned short*)((char*)d_ws + (size_t)N_ * V_ * D_ * 2); // +32 MiB

    (void)hipFuncSetAttribute(reinterpret_cast<const void*>(gemm3),
                              hipFuncAttributeMaxDynamicSharedMemorySize, 65536);

    prep<<<dim3(2048 + 8192), dim3(256), 0, stream>>>(ie, fts, emb, gam, bet, W, H, Wt);
    gemm3<<<dim3(1024), dim3(512), 65536, stream>>>(H, Wt, bp, out);
}

// Round 10
// 251.954 us; speedup vs baseline: 5.7424x; 5.7424x over previous
//
#include <hip/hip_runtime.h>
#include <hip/hip_bf16.h>

#define B_ 2048
#define N_ 8
#define D_ 1024
#define V_ 4096
#define LN_EPS_ 1e-5f

typedef __bf16 bf16x8 __attribute__((ext_vector_type(8)));
typedef float f32x4 __attribute__((ext_vector_type(4)));

#define GLB(p) ((const __attribute__((address_space(1))) void*)(p))
#define LDSP(p) ((__attribute__((address_space(3))) void*)(p))

static __device__ __forceinline__ unsigned short f2bf(float x) {
    union { float f; unsigned int u; } v;
    v.f = x;
    unsigned int r = v.u + 0x7fffu + ((v.u >> 16) & 1u);
    return (unsigned short)(r >> 16);
}

// ---------------------------------------------------------------------------
// prep: fused  (a) W_pred (N,D,V) f32 -> Wt (N,V,D) bf16   [blocks 2048..10239]
//              (b) gather+cumsum+LN+GELU -> H (N,B,D) bf16 [blocks 0..2047]
// ---------------------------------------------------------------------------
__global__ __launch_bounds__(256) void prep(const float* __restrict__ ie,
                                            const int* __restrict__ feats,
                                            const float* __restrict__ emb,
                                            const float* __restrict__ gamma,
                                            const float* __restrict__ beta,
                                            const float* __restrict__ W,
                                            unsigned short* __restrict__ H,
                                            unsigned short* __restrict__ Wt) {
    const int bid = blockIdx.x;
    const int t = threadIdx.x;

    if (bid >= 2048) {
        __shared__ unsigned short tile[64][65];
        const int w  = bid - 2048;
        const int v0 = (w & 63) * 64;
        const int d0 = ((w >> 6) & 15) * 64;
        const int n  = w >> 10;
        const int tx = t & 15, ty = t >> 4;
#pragma unroll
        for (int i = 0; i < 4; ++i) {
            const int d = ty + i * 16;
            const float4 w4 = *(const float4*)&W[((size_t)n * D_ + d0 + d) * V_ + v0 + tx * 4];
            tile[d][tx * 4 + 0] = f2bf(w4.x);
            tile[d][tx * 4 + 1] = f2bf(w4.y);
            tile[d][tx * 4 + 2] = f2bf(w4.z);
            tile[d][tx * 4 + 3] = f2bf(w4.w);
        }
        __syncthreads();
#pragma unroll
        for (int i = 0; i < 4; ++i) {
            const int v = ty + i * 16;
            ushort4 pk;
            pk.x = tile[tx * 4 + 0][v];
            pk.y = tile[tx * 4 + 1][v];
            pk.z = tile[tx * 4 + 2][v];
            pk.w = tile[tx * 4 + 3][v];
            *reinterpret_cast<ushort4*>(&Wt[((size_t)n * V_ + v0 + v) * D_ + d0 + tx * 4]) = pk;
        }
    } else {
        __shared__ float redS[4], redQ[4];
        const int b = bid;
        const int d0 = t * 4;
        const int lane = t & 63, wid = t >> 6;

        float4 s  = *(const float4*)&ie[(size_t)b * D_ + d0];
        const float4 g4 = *(const float4*)&gamma[d0];
        const float4 be4 = *(const float4*)&beta[d0];

        int fc[N_];
#pragma unroll
        for (int n = 0; n < N_; ++n) fc[n] = feats[b * N_ + n];

#pragma unroll
        for (int n = 0; n < N_; ++n) {
            float ls = s.x + s.y + s.z + s.w;
            float lq = s.x * s.x + s.y * s.y + s.z * s.z + s.w * s.w;
#pragma unroll
            for (int off = 32; off > 0; off >>= 1) {
                ls += __shfl_down(ls, off, 64);
                lq += __shfl_down(lq, off, 64);
            }
            if (lane == 0) { redS[wid] = ls; redQ[wid] = lq; }
            __syncthreads();
            const float tot  = redS[0] + redS[1] + redS[2] + redS[3];
            const float totq = redQ[0] + redQ[1] + redQ[2] + redQ[3];
            __syncthreads();

            const float mu   = tot * (1.0f / D_);
            const float var  = totq * (1.0f / D_) - mu * mu;
            const float rstd = rsqrtf(var + LN_EPS_);

            float h0 = (s.x - mu) * rstd * g4.x + be4.x;
            float h1 = (s.y - mu) * rstd * g4.y + be4.y;
            float h2 = (s.z - mu) * rstd * g4.z + be4.z;
            float h3 = (s.w - mu) * rstd * g4.w + be4.w;
            h0 = 0.5f * h0 * (1.0f + erff(h0 * 0.70710678f));
            h1 = 0.5f * h1 * (1.0f + erff(h1 * 0.70710678f));
            h2 = 0.5f * h2 * (1.0f + erff(h2 * 0.70710678f));
            h3 = 0.5f * h3 * (1.0f + erff(h3 * 0.70710678f));

            ushort4 pk;
            pk.x = f2bf(h0); pk.y = f2bf(h1); pk.z = f2bf(h2); pk.w = f2bf(h3);
            *reinterpret_cast<ushort4*>(&H[((size_t)n * B_ + b) * D_ + d0]) = pk;

            const float4 e = *(const float4*)&emb[((size_t)n * V_ + fc[n]) * (size_t)D_ + d0];
            s.x += e.x; s.y += e.y; s.z += e.z; s.w += e.w;
        }
    }
}

// ---------------------------------------------------------------------------
// gemm3: 256x256 tile, BK=32, 8 waves (2x4, wave-tile 128x64).
// TWO blocks per CU via LDS = 2 buffers x 32KB = 64KB (160/64 -> 2 resident).
// __launch_bounds__(512, 2): NO VGPR clamp (R9's (512,4) forced 64 VGPR ->
// accumulator spill -> 6.8GB scratch traffic). 2 blocks x 8 waves = 4
// waves/SIMD x ~112 VGPR = well within the 2048/SIMD pool.
// Per tile: vmcnt(0) -> barrier -> 12 ds_read_b128 + stage t+1 -> 2x16 MFMA
// (setprio) -> barrier. Inter-block overlap hides the vmcnt/barrier drain.
// Swizzle (R7-verified, 0 conflicts): phys 16B slot = logical ^ ((row>>1)&3),
// inverse pre-applied on the global source.
// ---------------------------------------------------------------------------
#define MF(a, b, c) __builtin_amdgcn_mfma_f32_16x16x32_bf16((a), (b), (c), 0, 0, 0)

#define STAGE2(KS, bb) { \
    __builtin_amdgcn_global_load_lds(GLB(Ab + (KS) + (size_t)(srow      ) * D_ + gsl), LDSP(lds + (bb) +         t * 16), 16, 0, 0); \
    __builtin_amdgcn_global_load_lds(GLB(Ab + (KS) + (size_t)(srow + 128) * D_ + gsl), LDSP(lds + (bb) +  8192 + t * 16), 16, 0, 0); \
    __builtin_amdgcn_global_load_lds(GLB(Bb + (KS) + (size_t)(srow      ) * D_ + gsl), LDSP(lds + (bb) + 16384 + t * 16), 16, 0, 0); \
    __builtin_amdgcn_global_load_lds(GLB(Bb + (KS) + (size_t)(srow + 128) * D_ + gsl), LDSP(lds + (bb) + 24576 + t * 16), 16, 0, 0); \
}

#define RD_A2(i, bb) (*(const bf16x8*)(lds + (bb) + ((i) * 32 + wr * 16 + lrow) * 64 + swk))
#define RD_B2(j, bb) (*(const bf16x8*)(lds + (bb) + 16384 + (wc * 64 + (j) * 16 + lrow) * 64 + swk))

#define TILE3(bc, bn, KS, DOSTG) { \
    asm volatile("s_waitcnt vmcnt(0)" ::: "memory"); \
    __builtin_amdgcn_s_barrier(); \
    bf16x8 Bf[4], Af[4]; \
    _Pragma("unroll") for (int j = 0; j < 4; ++j) Bf[j] = RD_B2(j, bc); \
    _Pragma("unroll") for (int i = 0; i < 4; ++i) Af[i] = RD_A2(i, bc); \
    if (DOSTG) { STAGE2(KS, bn); } \
    __builtin_amdgcn_s_setprio(1); \
    _Pragma("unroll") for (int i = 0; i < 4; ++i) \
        _Pragma("unroll") for (int j = 0; j < 4; ++j) \
            acc[i][j] = MF(Af[i], Bf[j], acc[i][j]); \
    __builtin_amdgcn_s_setprio(0); \
    _Pragma("unroll") for (int i = 0; i < 4; ++i) Af[i] = RD_A2((i) + 4, bc); \
    __builtin_amdgcn_s_setprio(1); \
    _Pragma("unroll") for (int i = 0; i < 4; ++i) \
        _Pragma("unroll") for (int j = 0; j < 4; ++j) \
            acc[i + 4][j] = MF(Af[i], Bf[j], acc[i + 4][j]); \
    __builtin_amdgcn_s_setprio(0); \
    __builtin_amdgcn_s_barrier(); \
}

__global__ __launch_bounds__(512, 2) void gemm3(const unsigned short* __restrict__ H,
                                                const unsigned short* __restrict__ Wt,
                                                const float* __restrict__ bp,
                                                float* __restrict__ out) {
    extern __shared__ char lds[];
    const int bid = blockIdx.x;
    // XCD chunking: XCD k (= bid&7) owns logical range [128k,128k+128) = one n
    const int logical = (bid & 7) * 128 + (bid >> 3);
    const int n  = logical >> 7;
    const int mt = (logical >> 4) & 7;
    const int vt = logical & 15;

    const int t = threadIdx.x;
    const int wid = t >> 6, lane = t & 63;
    const int wr = wid >> 2, wc = wid & 3;

    const unsigned short* Ab = H  + ((size_t)n * B_ + (size_t)mt * 256) * D_;
    const unsigned short* Bb = Wt + ((size_t)n * V_ + (size_t)vt * 256) * D_;

    const int srow = t >> 2;                              // 0..127
    const int gsl  = ((t & 3) ^ ((t >> 3) & 3)) * 8;      // inverse-swizzled source slot
    const int lrow = lane & 15;
    const int lkq  = lane >> 4;
    const int swk  = (lkq ^ ((lrow >> 1) & 3)) * 16;      // 2-way-free read swizzle
    const int col  = lane & 15;
    const int rg   = (lane >> 4) * 4;

    // bias (drained before pipeline)
    float bias[4];
#pragma unroll
    for (int j = 0; j < 4; ++j)
        bias[j] = bp[(size_t)n * V_ + vt * 256 + wc * 64 + j * 16 + col];
    asm volatile("s_waitcnt vmcnt(0)" ::: "memory");
    __builtin_amdgcn_sched_barrier(0);

    f32x4 acc[8][4] = {};

    // prologue: stage tile 0 into buf0
    STAGE2(0, 0);

#pragma unroll 1
    for (int it = 0; it < 15; ++it) {       // tiles 0..29, staging 1..30
        const int ks = it * 64 + 32;
        TILE3(0,     32768, ks,      1);    // compute 2it,   stage 2it+1
        TILE3(32768, 0,     ks + 32, 1);    // compute 2it+1, stage 2it+2
    }
    TILE3(0,     32768, 992, 1);            // tile 30, stages tile 31
    TILE3(32768, 0,     0,   0);            // tile 31 (no stage)

    // epilogue: C/D layout col = lane&15, row = (lane>>4)*4 + reg
    const int gc0 = vt * 256 + wc * 64 + col;
#pragma unroll
    for (int i = 0; i < 8; ++i) {
        const int row = mt * 256 + i * 32 + wr * 16 + rg;
#pragma unroll
        for (int j = 0; j < 4; ++j) {
            const int gcol = gc0 + j * 16;
#pragma unroll
            for (int r = 0; r < 4; ++r)
                out[((size_t)(row + r) * N_ + n) * V_ + gcol] = acc[i][j][r] + bias[j];
        }
    }
}

// ---------------------------------------------------------------------------
extern "C" void kernel_launch(void* const* d_in, const int* in_sizes, int n_in,
                              void* d_out, int out_size, void* d_ws, size_t ws_size,
                              hipStream_t stream) {
    const float* ie  = (const float*)d_in[0];
    const int*   fts = (const int*)d_in[1];
    const float* emb = (const float*)d_in[2];
    const float* W   = (const float*)d_in[3];
    const float* bp  = (const float*)d_in[4];
    const float* gam = (const float*)d_in[5];
    const float* bet = (const float*)d_in[6];
    float* out = (float*)d_out;

    unsigned short* Wt = (unsigned short*)d_ws;                                     // 64 MiB
    unsigned short* H  = (unsigned short*)((char*)d_ws + (size_t)N_ * V_ * D_ * 2); // +32 MiB

    (void)hipFuncSetAttribute(reinterpret_cast<const void*>(gemm3),
                              hipFuncAttributeMaxDynamicSharedMemorySize, 65536);

    prep<<<dim3(2048 + 8192), dim3(256), 0, stream>>>(ie, fts, emb, gam, bet, W, H, Wt);
    gemm3<<<dim3(1024), dim3(512), 65536, stream>>>(H, Wt, bp, out);
}

// Round 11
// 235.264 us; speedup vs baseline: 6.1498x; 1.0709x over previous
//
#include <hip/hip_runtime.h>
#include <hip/hip_bf16.h>

#define B_ 2048
#define N_ 8
#define D_ 1024
#define V_ 4096
#define LN_EPS_ 1e-5f

typedef __bf16 bf16x8 __attribute__((ext_vector_type(8)));
typedef float f32x16 __attribute__((ext_vector_type(16)));

#define GLB(p) ((const __attribute__((address_space(1))) void*)(p))
#define LDSP(p) ((__attribute__((address_space(3))) void*)(p))

static __device__ __forceinline__ unsigned short f2bf(float x) {
    union { float f; unsigned int u; } v;
    v.f = x;
    unsigned int r = v.u + 0x7fffu + ((v.u >> 16) & 1u);
    return (unsigned short)(r >> 16);
}

// ---------------------------------------------------------------------------
// K-plane-major granule layouts (granule = 8 consecutive k/d elements = 16B):
//   H2  element off = n*2097152 + rb*32768 + kq*256 + r*8 + e   (rb=row>>5, r=row&31, kq=d>>3)
//   Wt2 element off = n*4194304 + cb*32768 + kq*256 + c*8 + e   (cb=col>>5, c=col&31)
// MFMA 32x32x16 fragment (on-device verified, R5): lane reads granule at
// (row|col = lane&31, kq = 2*ks + (lane>>5)) -> 512B contiguous per 32 lanes.
// ---------------------------------------------------------------------------

// prep: (a) W_pred (N,D,V) f32 -> Wt2  [blocks 2048..10239]
//       (b) gather+cumsum+LN+GELU -> H2 [blocks 0..2047]
__global__ __launch_bounds__(256) void prep(const float* __restrict__ ie,
                                            const int* __restrict__ feats,
                                            const float* __restrict__ emb,
                                            const float* __restrict__ gamma,
                                            const float* __restrict__ beta,
                                            const float* __restrict__ W,
                                            unsigned short* __restrict__ H,
                                            unsigned short* __restrict__ Wt) {
    const int bid = blockIdx.x;
    const int t = threadIdx.x;

    if (bid >= 2048) {
        __shared__ unsigned short tile[64][65];
        const int w  = bid - 2048;
        const int v0 = (w & 63) * 64;
        const int d0 = ((w >> 6) & 15) * 64;
        const int n  = w >> 10;
        const int tx = t & 15, ty = t >> 4;
#pragma unroll
        for (int i = 0; i < 4; ++i) {
            const int d = ty + i * 16;
            const float4 w4 = *(const float4*)&W[((size_t)n * D_ + d0 + d) * V_ + v0 + tx * 4];
            tile[d][tx * 4 + 0] = f2bf(w4.x);
            tile[d][tx * 4 + 1] = f2bf(w4.y);
            tile[d][tx * 4 + 2] = f2bf(w4.z);
            tile[d][tx * 4 + 3] = f2bf(w4.w);
        }
        __syncthreads();
        // write 2 granules per thread into Wt2 K-plane layout
#pragma unroll
        for (int p = 0; p < 2; ++p) {
            const int g   = t + p * 256;          // 0..511
            const int c   = g & 31;
            const int cbl = (g >> 5) & 1;
            const int kq  = g >> 6;               // 0..7
            ushort4 lo, hi;
            lo.x = tile[kq * 8 + 0][cbl * 32 + c];
            lo.y = tile[kq * 8 + 1][cbl * 32 + c];
            lo.z = tile[kq * 8 + 2][cbl * 32 + c];
            lo.w = tile[kq * 8 + 3][cbl * 32 + c];
            hi.x = tile[kq * 8 + 4][cbl * 32 + c];
            hi.y = tile[kq * 8 + 5][cbl * 32 + c];
            hi.z = tile[kq * 8 + 6][cbl * 32 + c];
            hi.w = tile[kq * 8 + 7][cbl * 32 + c];
            const size_t goff = (size_t)n * 4194304 + (size_t)((v0 >> 5) + cbl) * 32768
                              + (size_t)((d0 >> 3) + kq) * 256 + c * 8;
            *reinterpret_cast<ushort4*>(&Wt[goff])     = lo;
            *reinterpret_cast<ushort4*>(&Wt[goff + 4]) = hi;
        }
    } else {
        __shared__ float redS[4], redQ[4];
        const int b = bid;
        const int d0 = t * 4;
        const int lane = t & 63, wid = t >> 6;

        float4 s  = *(const float4*)&ie[(size_t)b * D_ + d0];
        const float4 g4 = *(const float4*)&gamma[d0];
        const float4 be4 = *(const float4*)&beta[d0];

        int fc[N_];
#pragma unroll
        for (int n = 0; n < N_; ++n) fc[n] = feats[b * N_ + n];

        // H2 per-thread offset: kq = t>>1, e0 = (t&1)*4, rb = b>>5, r = b&31
        const size_t hbase = (size_t)(b >> 5) * 32768 + (size_t)(t >> 1) * 256
                           + (b & 31) * 8 + (t & 1) * 4;

#pragma unroll
        for (int n = 0; n < N_; ++n) {
            float ls = s.x + s.y + s.z + s.w;
            float lq = s.x * s.x + s.y * s.y + s.z * s.z + s.w * s.w;
#pragma unroll
            for (int off = 32; off > 0; off >>= 1) {
                ls += __shfl_down(ls, off, 64);
                lq += __shfl_down(lq, off, 64);
            }
            if (lane == 0) { redS[wid] = ls; redQ[wid] = lq; }
            __syncthreads();
            const float tot  = redS[0] + redS[1] + redS[2] + redS[3];
            const float totq = redQ[0] + redQ[1] + redQ[2] + redQ[3];
            __syncthreads();

            const float mu   = tot * (1.0f / D_);
            const float var  = totq * (1.0f / D_) - mu * mu;
            const float rstd = rsqrtf(var + LN_EPS_);

            float h0 = (s.x - mu) * rstd * g4.x + be4.x;
            float h1 = (s.y - mu) * rstd * g4.y + be4.y;
            float h2 = (s.z - mu) * rstd * g4.z + be4.z;
            float h3 = (s.w - mu) * rstd * g4.w + be4.w;
            h0 = 0.5f * h0 * (1.0f + erff(h0 * 0.70710678f));
            h1 = 0.5f * h1 * (1.0f + erff(h1 * 0.70710678f));
            h2 = 0.5f * h2 * (1.0f + erff(h2 * 0.70710678f));
            h3 = 0.5f * h3 * (1.0f + erff(h3 * 0.70710678f));

            ushort4 pk;
            pk.x = f2bf(h0); pk.y = f2bf(h1); pk.z = f2bf(h2); pk.w = f2bf(h3);
            *reinterpret_cast<ushort4*>(&H[(size_t)n * 2097152 + hbase]) = pk;

            const float4 e = *(const float4*)&emb[((size_t)n * V_ + fc[n]) * (size_t)D_ + d0];
            s.x += e.x; s.y += e.y; s.z += e.z; s.w += e.w;
        }
    }
}

// ---------------------------------------------------------------------------
// gemm32: 256x256xBK64, 8 waves (2x4), mfma_f32_32x32x16_bf16, R7 cadence
// (4 phases, double barrier, counted vmcnt 3/4/4/6). LDS 2 x 64KB, no swizzle:
// K-plane-major units [rb2][kq][r] x16B; ds_read_b128 = contiguous 512B/32 lanes.
// Wave (wr,wc): rows {p*64 + wr*32}, cols wc*64 + j*32. Phase p computes band p
// (A unit p), stages 2 units of next tile (B0B1|B2B3|A0A1|A2A3).
// ---------------------------------------------------------------------------
#define MF32(a, b, c) __builtin_amdgcn_mfma_f32_32x32x16_bf16((a), (b), (c), 0, 0, 0)

#define STG_A(u, KTQ, bb) __builtin_amdgcn_global_load_lds( \
    GLB(Ab + (u) * 65536 + (KTQ) * 256), LDSP(lds + (bb) + (u) * 8192 + t * 16), 16, 0, 0)
#define STG_B(u, KTQ, bb) __builtin_amdgcn_global_load_lds( \
    GLB(Bb + (u) * 65536 + (KTQ) * 256), LDSP(lds + (bb) + 32768 + (u) * 8192 + t * 16), 16, 0, 0)

#define RD_A32(p, ks, bb) (*(const bf16x8*)(lds + (bb) + (p) * 8192 + wr * 4096 + ((ks) * 2 + h) * 512 + l31 * 16))
#define RD_B32(j, ks, bb) (*(const bf16x8*)(lds + (bb) + 32768 + wc * 8192 + (j) * 4096 + ((ks) * 2 + h) * 512 + l31 * 16))

#define MMP(p) \
    acc[p][0] = MF32(Af[0], Bf0[0], acc[p][0]); acc[p][1] = MF32(Af[0], Bf1[0], acc[p][1]); \
    acc[p][0] = MF32(Af[1], Bf0[1], acc[p][0]); acc[p][1] = MF32(Af[1], Bf1[1], acc[p][1]); \
    acc[p][0] = MF32(Af[2], Bf0[2], acc[p][0]); acc[p][1] = MF32(Af[2], Bf1[2], acc[p][1]); \
    acc[p][0] = MF32(Af[3], Bf0[3], acc[p][0]); acc[p][1] = MF32(Af[3], Bf1[3], acc[p][1]);

#define TILE32(bc, bn, KTQN) { \
    bf16x8 Bf0[4], Bf1[4], Af[4]; \
    asm volatile("s_waitcnt vmcnt(3)" ::: "memory"); \
    __builtin_amdgcn_s_barrier(); \
    _Pragma("unroll") for (int ks = 0; ks < 4; ++ks) { Bf0[ks] = RD_B32(0, ks, bc); Bf1[ks] = RD_B32(1, ks, bc); } \
    _Pragma("unroll") for (int ks = 0; ks < 4; ++ks) Af[ks] = RD_A32(0, ks, bc); \
    STG_B(0, KTQN, bn); STG_B(1, KTQN, bn); \
    __builtin_amdgcn_s_setprio(1); MMP(0); __builtin_amdgcn_s_setprio(0); \
    __builtin_amdgcn_s_barrier(); \
    asm volatile("s_waitcnt vmcnt(4)" ::: "memory"); \
    __builtin_amdgcn_s_barrier(); \
    _Pragma("unroll") for (int ks = 0; ks < 4; ++ks) Af[ks] = RD_A32(1, ks, bc); \
    STG_B(2, KTQN, bn); STG_B(3, KTQN, bn); \
    __builtin_amdgcn_s_setprio(1); MMP(1); __builtin_amdgcn_s_setprio(0); \
    __builtin_amdgcn_s_barrier(); \
    asm volatile("s_waitcnt vmcnt(4)" ::: "memory"); \
    __builtin_amdgcn_s_barrier(); \
    _Pragma("unroll") for (int ks = 0; ks < 4; ++ks) Af[ks] = RD_A32(2, ks, bc); \
    STG_A(0, KTQN, bn); STG_A(1, KTQN, bn); \
    __builtin_amdgcn_s_setprio(1); MMP(2); __builtin_amdgcn_s_setprio(0); \
    __builtin_amdgcn_s_barrier(); \
    asm volatile("s_waitcnt vmcnt(6)" ::: "memory"); \
    __builtin_amdgcn_s_barrier(); \
    _Pragma("unroll") for (int ks = 0; ks < 4; ++ks) Af[ks] = RD_A32(3, ks, bc); \
    STG_A(2, KTQN, bn); STG_A(3, KTQN, bn); \
    __builtin_amdgcn_s_setprio(1); MMP(3); __builtin_amdgcn_s_setprio(0); \
    __builtin_amdgcn_s_barrier(); \
}

#define TILE32_LAST(bc) { \
    bf16x8 Bf0[4], Bf1[4], Af[4]; \
    asm volatile("s_waitcnt vmcnt(3)" ::: "memory"); \
    __builtin_amdgcn_s_barrier(); \
    _Pragma("unroll") for (int ks = 0; ks < 4; ++ks) { Bf0[ks] = RD_B32(0, ks, bc); Bf1[ks] = RD_B32(1, ks, bc); } \
    _Pragma("unroll") for (int ks = 0; ks < 4; ++ks) Af[ks] = RD_A32(0, ks, bc); \
    __builtin_amdgcn_s_setprio(1); MMP(0); __builtin_amdgcn_s_setprio(0); \
    __builtin_amdgcn_s_barrier(); \
    asm volatile("s_waitcnt vmcnt(2)" ::: "memory"); \
    __builtin_amdgcn_s_barrier(); \
    _Pragma("unroll") for (int ks = 0; ks < 4; ++ks) Af[ks] = RD_A32(1, ks, bc); \
    __builtin_amdgcn_s_setprio(1); MMP(1); __builtin_amdgcn_s_setprio(0); \
    __builtin_amdgcn_s_barrier(); \
    asm volatile("s_waitcnt vmcnt(1)" ::: "memory"); \
    __builtin_amdgcn_s_barrier(); \
    _Pragma("unroll") for (int ks = 0; ks < 4; ++ks) Af[ks] = RD_A32(2, ks, bc); \
    __builtin_amdgcn_s_setprio(1); MMP(2); __builtin_amdgcn_s_setprio(0); \
    __builtin_amdgcn_s_barrier(); \
    asm volatile("s_waitcnt vmcnt(0)" ::: "memory"); \
    __builtin_amdgcn_s_barrier(); \
    _Pragma("unroll") for (int ks = 0; ks < 4; ++ks) Af[ks] = RD_A32(3, ks, bc); \
    __builtin_amdgcn_s_setprio(1); MMP(3); __builtin_amdgcn_s_setprio(0); \
}

__global__ __launch_bounds__(512, 2) void gemm32(const unsigned short* __restrict__ H,
                                                 const unsigned short* __restrict__ Wt,
                                                 const float* __restrict__ bp,
                                                 float* __restrict__ out) {
    extern __shared__ char lds[];
    const int bid = blockIdx.x;
    // XCD chunking: XCD k (= bid&7) owns logical range [128k,128k+128) = one n
    const int logical = (bid & 7) * 128 + (bid >> 3);
    const int n  = logical >> 7;
    const int mt = (logical >> 4) & 7;
    const int vt = logical & 15;

    const int t = threadIdx.x;
    const int wid = t >> 6, lane = t & 63;
    const int wr = wid >> 2, wc = wid & 3;
    const int h = lane >> 5, l31 = lane & 31;

    // staging source bases (per-thread): unit layout [rb2(t>>8)][kq((t>>5)&7)][r(t&31)]
    const unsigned short* Ab = H  + (size_t)n * 2097152 + (size_t)mt * 262144
                             + (t >> 8) * 32768 + ((t >> 5) & 7) * 256 + (t & 31) * 8;
    const unsigned short* Bb = Wt + (size_t)n * 4194304 + (size_t)vt * 262144
                             + (t >> 8) * 32768 + ((t >> 5) & 7) * 256 + (t & 31) * 8;

    // bias (drained before pipeline)
    float bias[2];
#pragma unroll
    for (int j = 0; j < 2; ++j)
        bias[j] = bp[(size_t)n * V_ + vt * 256 + wc * 64 + j * 32 + l31];
    asm volatile("s_waitcnt vmcnt(0)" ::: "memory");
    __builtin_amdgcn_sched_barrier(0);

    f32x16 acc[4][2];
#pragma unroll
    for (int p = 0; p < 4; ++p)
#pragma unroll
        for (int r = 0; r < 16; ++r) { acc[p][0][r] = 0.f; acc[p][1][r] = 0.f; }

    // prologue: stage tile 0 into buf0 (B0 B1 B2 B3 A0 A1 A2 A3)
    STG_B(0, 0, 0); STG_B(1, 0, 0); STG_B(2, 0, 0); STG_B(3, 0, 0);
    STG_A(0, 0, 0); STG_A(1, 0, 0); STG_A(2, 0, 0); STG_A(3, 0, 0);

    int ktq = 0;
#pragma unroll 1
    for (int it = 0; it < 7; ++it) {          // tiles 0..13
        TILE32(0, 65536, ktq + 8);  ktq += 8;
        TILE32(65536, 0, ktq + 8);  ktq += 8;
    }
    TILE32(0, 65536, 120);                    // tile 14 (stages tile 15)
    TILE32_LAST(65536);                       // tile 15

    // epilogue: C/D (verified m74/m101): col=lane&31, row=(reg&3)+8*(reg>>2)+4*h
    const int gc0 = vt * 256 + wc * 64 + l31;
#pragma unroll
    for (int p = 0; p < 4; ++p) {
#pragma unroll
        for (int j = 0; j < 2; ++j) {
            const int gcol = gc0 + j * 32;
#pragma unroll
            for (int r = 0; r < 16; ++r) {
                const int row = mt * 256 + p * 64 + wr * 32 + (r & 3) + 8 * (r >> 2) + 4 * h;
                out[((size_t)row * N_ + n) * V_ + gcol] = acc[p][j][r] + bias[j];
            }
        }
    }
}

// ---------------------------------------------------------------------------
extern "C" void kernel_launch(void* const* d_in, const int* in_sizes, int n_in,
                              void* d_out, int out_size, void* d_ws, size_t ws_size,
                              hipStream_t stream) {
    const float* ie  = (const float*)d_in[0];
    const int*   fts = (const int*)d_in[1];
    const float* emb = (const float*)d_in[2];
    const float* W   = (const float*)d_in[3];
    const float* bp  = (const float*)d_in[4];
    const float* gam = (const float*)d_in[5];
    const float* bet = (const float*)d_in[6];
    float* out = (float*)d_out;

    unsigned short* Wt = (unsigned short*)d_ws;                                     // 64 MiB (K-plane layout)
    unsigned short* H  = (unsigned short*)((char*)d_ws + (size_t)N_ * V_ * D_ * 2); // +32 MiB (K-plane layout)

    (void)hipFuncSetAttribute(reinterpret_cast<const void*>(gemm32),
                              hipFuncAttributeMaxDynamicSharedMemorySize, 131072);

    prep<<<dim3(2048 + 8192), dim3(256), 0, stream>>>(ie, fts, emb, gam, bet, W, H, Wt);
    gemm32<<<dim3(1024), dim3(512), 131072, stream>>>(H, Wt, bp, out);
}

// Round 12
// 234.321 us; speedup vs baseline: 6.1746x; 1.0040x over previous
//
#include <hip/hip_runtime.h>
#include <hip/hip_bf16.h>

#define B_ 2048
#define N_ 8
#define D_ 1024
#define V_ 4096
#define LN_EPS_ 1e-5f

typedef __bf16 bf16x8 __attribute__((ext_vector_type(8)));
typedef float f32x16 __attribute__((ext_vector_type(16)));

#define GLB(p) ((const __attribute__((address_space(1))) void*)(p))
#define LDSP(p) ((__attribute__((address_space(3))) void*)(p))

static __device__ __forceinline__ unsigned short f2bf(float x) {
    union { float f; unsigned int u; } v;
    v.f = x;
    unsigned int r = v.u + 0x7fffu + ((v.u >> 16) & 1u);
    return (unsigned short)(r >> 16);
}

// ---------------------------------------------------------------------------
// K-plane-major granule layouts (granule = 8 consecutive k/d elements = 16B):
//   H2  element off = n*2097152 + rb*32768 + kq*256 + r*8 + e
//   Wt2 element off = n*4194304 + cb*32768 + kq*256 + c*8 + e
// ---------------------------------------------------------------------------

// prep: (a) W_pred (N,D,V) f32 -> Wt2  [blocks 2048..10239]
//       (b) gather+cumsum+LN+GELU -> H2 [blocks 0..2047]
// R11->R12: stage1 hoists all 8 gather loads; single barrier per n via
// double-buffered reduction scratch.
__global__ __launch_bounds__(256) void prep(const float* __restrict__ ie,
                                            const int* __restrict__ feats,
                                            const float* __restrict__ emb,
                                            const float* __restrict__ gamma,
                                            const float* __restrict__ beta,
                                            const float* __restrict__ W,
                                            unsigned short* __restrict__ H,
                                            unsigned short* __restrict__ Wt) {
    const int bid = blockIdx.x;
    const int t = threadIdx.x;

    if (bid >= 2048) {
        __shared__ unsigned short tile[64][65];
        const int w  = bid - 2048;
        const int v0 = (w & 63) * 64;
        const int d0 = ((w >> 6) & 15) * 64;
        const int n  = w >> 10;
        const int tx = t & 15, ty = t >> 4;
#pragma unroll
        for (int i = 0; i < 4; ++i) {
            const int d = ty + i * 16;
            const float4 w4 = *(const float4*)&W[((size_t)n * D_ + d0 + d) * V_ + v0 + tx * 4];
            tile[d][tx * 4 + 0] = f2bf(w4.x);
            tile[d][tx * 4 + 1] = f2bf(w4.y);
            tile[d][tx * 4 + 2] = f2bf(w4.z);
            tile[d][tx * 4 + 3] = f2bf(w4.w);
        }
        __syncthreads();
#pragma unroll
        for (int p = 0; p < 2; ++p) {
            const int g   = t + p * 256;
            const int c   = g & 31;
            const int cbl = (g >> 5) & 1;
            const int kq  = g >> 6;
            ushort4 lo, hi;
            lo.x = tile[kq * 8 + 0][cbl * 32 + c];
            lo.y = tile[kq * 8 + 1][cbl * 32 + c];
            lo.z = tile[kq * 8 + 2][cbl * 32 + c];
            lo.w = tile[kq * 8 + 3][cbl * 32 + c];
            hi.x = tile[kq * 8 + 4][cbl * 32 + c];
            hi.y = tile[kq * 8 + 5][cbl * 32 + c];
            hi.z = tile[kq * 8 + 6][cbl * 32 + c];
            hi.w = tile[kq * 8 + 7][cbl * 32 + c];
            const size_t goff = (size_t)n * 4194304 + (size_t)((v0 >> 5) + cbl) * 32768
                              + (size_t)((d0 >> 3) + kq) * 256 + c * 8;
            *reinterpret_cast<ushort4*>(&Wt[goff])     = lo;
            *reinterpret_cast<ushort4*>(&Wt[goff + 4]) = hi;
        }
    } else {
        __shared__ float redS[2][4], redQ[2][4];
        const int b = bid;
        const int d0 = t * 4;
        const int lane = t & 63, wid = t >> 6;

        float4 s  = *(const float4*)&ie[(size_t)b * D_ + d0];
        const float4 g4 = *(const float4*)&gamma[d0];
        const float4 be4 = *(const float4*)&beta[d0];

        int fc[N_];
#pragma unroll
        for (int n = 0; n < N_; ++n) fc[n] = feats[b * N_ + n];

        // hoist all 8 gather rows (independent of the cumsum chain)
        float4 ev[N_];
#pragma unroll
        for (int n = 0; n < N_; ++n)
            ev[n] = *(const float4*)&emb[((size_t)n * V_ + fc[n]) * (size_t)D_ + d0];

        const size_t hbase = (size_t)(b >> 5) * 32768 + (size_t)(t >> 1) * 256
                           + (b & 31) * 8 + (t & 1) * 4;

#pragma unroll
        for (int n = 0; n < N_; ++n) {
            float ls = s.x + s.y + s.z + s.w;
            float lq = s.x * s.x + s.y * s.y + s.z * s.z + s.w * s.w;
#pragma unroll
            for (int off = 32; off > 0; off >>= 1) {
                ls += __shfl_down(ls, off, 64);
                lq += __shfl_down(lq, off, 64);
            }
            const int sl = n & 1;
            if (lane == 0) { redS[sl][wid] = ls; redQ[sl][wid] = lq; }
            __syncthreads();
            const float tot  = redS[sl][0] + redS[sl][1] + redS[sl][2] + redS[sl][3];
            const float totq = redQ[sl][0] + redQ[sl][1] + redQ[sl][2] + redQ[sl][3];

            const float mu   = tot * (1.0f / D_);
            const float var  = totq * (1.0f / D_) - mu * mu;
            const float rstd = rsqrtf(var + LN_EPS_);

            float h0 = (s.x - mu) * rstd * g4.x + be4.x;
            float h1 = (s.y - mu) * rstd * g4.y + be4.y;
            float h2 = (s.z - mu) * rstd * g4.z + be4.z;
            float h3 = (s.w - mu) * rstd * g4.w + be4.w;
            h0 = 0.5f * h0 * (1.0f + erff(h0 * 0.70710678f));
            h1 = 0.5f * h1 * (1.0f + erff(h1 * 0.70710678f));
            h2 = 0.5f * h2 * (1.0f + erff(h2 * 0.70710678f));
            h3 = 0.5f * h3 * (1.0f + erff(h3 * 0.70710678f));

            ushort4 pk;
            pk.x = f2bf(h0); pk.y = f2bf(h1); pk.z = f2bf(h2); pk.w = f2bf(h3);
            *reinterpret_cast<ushort4*>(&H[(size_t)n * 2097152 + hbase]) = pk;

            s.x += ev[n].x; s.y += ev[n].y; s.z += ev[n].z; s.w += ev[n].w;
        }
    }
}

// ---------------------------------------------------------------------------
// gemm32 (FROZEN from R11): 256x256xBK64, 8 waves, mfma_f32_32x32x16_bf16,
// 4-phase double-barrier cadence, counted vmcnt 3/4/4/6, K-plane LDS layout
// (no swizzle, conflict-free). 164 us, 835 TF, 0 bank conflicts.
// ---------------------------------------------------------------------------
#define MF32(a, b, c) __builtin_amdgcn_mfma_f32_32x32x16_bf16((a), (b), (c), 0, 0, 0)

#define STG_A(u, KTQ, bb) __builtin_amdgcn_global_load_lds( \
    GLB(Ab + (u) * 65536 + (KTQ) * 256), LDSP(lds + (bb) + (u) * 8192 + t * 16), 16, 0, 0)
#define STG_B(u, KTQ, bb) __builtin_amdgcn_global_load_lds( \
    GLB(Bb + (u) * 65536 + (KTQ) * 256), LDSP(lds + (bb) + 32768 + (u) * 8192 + t * 16), 16, 0, 0)

#define RD_A32(p, ks, bb) (*(const bf16x8*)(lds + (bb) + (p) * 8192 + wr * 4096 + ((ks) * 2 + h) * 512 + l31 * 16))
#define RD_B32(j, ks, bb) (*(const bf16x8*)(lds + (bb) + 32768 + wc * 8192 + (j) * 4096 + ((ks) * 2 + h) * 512 + l31 * 16))

#define MMP(p) \
    acc[p][0] = MF32(Af[0], Bf0[0], acc[p][0]); acc[p][1] = MF32(Af[0], Bf1[0], acc[p][1]); \
    acc[p][0] = MF32(Af[1], Bf0[1], acc[p][0]); acc[p][1] = MF32(Af[1], Bf1[1], acc[p][1]); \
    acc[p][0] = MF32(Af[2], Bf0[2], acc[p][0]); acc[p][1] = MF32(Af[2], Bf1[2], acc[p][1]); \
    acc[p][0] = MF32(Af[3], Bf0[3], acc[p][0]); acc[p][1] = MF32(Af[3], Bf1[3], acc[p][1]);

#define TILE32(bc, bn, KTQN) { \
    bf16x8 Bf0[4], Bf1[4], Af[4]; \
    asm volatile("s_waitcnt vmcnt(3)" ::: "memory"); \
    __builtin_amdgcn_s_barrier(); \
    _Pragma("unroll") for (int ks = 0; ks < 4; ++ks) { Bf0[ks] = RD_B32(0, ks, bc); Bf1[ks] = RD_B32(1, ks, bc); } \
    _Pragma("unroll") for (int ks = 0; ks < 4; ++ks) Af[ks] = RD_A32(0, ks, bc); \
    STG_B(0, KTQN, bn); STG_B(1, KTQN, bn); \
    __builtin_amdgcn_s_setprio(1); MMP(0); __builtin_amdgcn_s_setprio(0); \
    __builtin_amdgcn_s_barrier(); \
    asm volatile("s_waitcnt vmcnt(4)" ::: "memory"); \
    __builtin_amdgcn_s_barrier(); \
    _Pragma("unroll") for (int ks = 0; ks < 4; ++ks) Af[ks] = RD_A32(1, ks, bc); \
    STG_B(2, KTQN, bn); STG_B(3, KTQN, bn); \
    __builtin_amdgcn_s_setprio(1); MMP(1); __builtin_amdgcn_s_setprio(0); \
    __builtin_amdgcn_s_barrier(); \
    asm volatile("s_waitcnt vmcnt(4)" ::: "memory"); \
    __builtin_amdgcn_s_barrier(); \
    _Pragma("unroll") for (int ks = 0; ks < 4; ++ks) Af[ks] = RD_A32(2, ks, bc); \
    STG_A(0, KTQN, bn); STG_A(1, KTQN, bn); \
    __builtin_amdgcn_s_setprio(1); MMP(2); __builtin_amdgcn_s_setprio(0); \
    __builtin_amdgcn_s_barrier(); \
    asm volatile("s_waitcnt vmcnt(6)" ::: "memory"); \
    __builtin_amdgcn_s_barrier(); \
    _Pragma("unroll") for (int ks = 0; ks < 4; ++ks) Af[ks] = RD_A32(3, ks, bc); \
    STG_A(2, KTQN, bn); STG_A(3, KTQN, bn); \
    __builtin_amdgcn_s_setprio(1); MMP(3); __builtin_amdgcn_s_setprio(0); \
    __builtin_amdgcn_s_barrier(); \
}

#define TILE32_LAST(bc) { \
    bf16x8 Bf0[4], Bf1[4], Af[4]; \
    asm volatile("s_waitcnt vmcnt(3)" ::: "memory"); \
    __builtin_amdgcn_s_barrier(); \
    _Pragma("unroll") for (int ks = 0; ks < 4; ++ks) { Bf0[ks] = RD_B32(0, ks, bc); Bf1[ks] = RD_B32(1, ks, bc); } \
    _Pragma("unroll") for (int ks = 0; ks < 4; ++ks) Af[ks] = RD_A32(0, ks, bc); \
    __builtin_amdgcn_s_setprio(1); MMP(0); __builtin_amdgcn_s_setprio(0); \
    __builtin_amdgcn_s_barrier(); \
    asm volatile("s_waitcnt vmcnt(2)" ::: "memory"); \
    __builtin_amdgcn_s_barrier(); \
    _Pragma("unroll") for (int ks = 0; ks < 4; ++ks) Af[ks] = RD_A32(1, ks, bc); \
    __builtin_amdgcn_s_setprio(1); MMP(1); __builtin_amdgcn_s_setprio(0); \
    __builtin_amdgcn_s_barrier(); \
    asm volatile("s_waitcnt vmcnt(1)" ::: "memory"); \
    __builtin_amdgcn_s_barrier(); \
    _Pragma("unroll") for (int ks = 0; ks < 4; ++ks) Af[ks] = RD_A32(2, ks, bc); \
    __builtin_amdgcn_s_setprio(1); MMP(2); __builtin_amdgcn_s_setprio(0); \
    __builtin_amdgcn_s_barrier(); \
    asm volatile("s_waitcnt vmcnt(0)" ::: "memory"); \
    __builtin_amdgcn_s_barrier(); \
    _Pragma("unroll") for (int ks = 0; ks < 4; ++ks) Af[ks] = RD_A32(3, ks, bc); \
    __builtin_amdgcn_s_setprio(1); MMP(3); __builtin_amdgcn_s_setprio(0); \
}

__global__ __launch_bounds__(512, 2) void gemm32(const unsigned short* __restrict__ H,
                                                 const unsigned short* __restrict__ Wt,
                                                 const float* __restrict__ bp,
                                                 float* __restrict__ out) {
    extern __shared__ char lds[];
    const int bid = blockIdx.x;
    const int logical = (bid & 7) * 128 + (bid >> 3);
    const int n  = logical >> 7;
    const int mt = (logical >> 4) & 7;
    const int vt = logical & 15;

    const int t = threadIdx.x;
    const int wid = t >> 6, lane = t & 63;
    const int wr = wid >> 2, wc = wid & 3;
    const int h = lane >> 5, l31 = lane & 31;

    const unsigned short* Ab = H  + (size_t)n * 2097152 + (size_t)mt * 262144
                             + (t >> 8) * 32768 + ((t >> 5) & 7) * 256 + (t & 31) * 8;
    const unsigned short* Bb = Wt + (size_t)n * 4194304 + (size_t)vt * 262144
                             + (t >> 8) * 32768 + ((t >> 5) & 7) * 256 + (t & 31) * 8;

    float bias[2];
#pragma unroll
    for (int j = 0; j < 2; ++j)
        bias[j] = bp[(size_t)n * V_ + vt * 256 + wc * 64 + j * 32 + l31];
    asm volatile("s_waitcnt vmcnt(0)" ::: "memory");
    __builtin_amdgcn_sched_barrier(0);

    f32x16 acc[4][2];
#pragma unroll
    for (int p = 0; p < 4; ++p)
#pragma unroll
        for (int r = 0; r < 16; ++r) { acc[p][0][r] = 0.f; acc[p][1][r] = 0.f; }

    STG_B(0, 0, 0); STG_B(1, 0, 0); STG_B(2, 0, 0); STG_B(3, 0, 0);
    STG_A(0, 0, 0); STG_A(1, 0, 0); STG_A(2, 0, 0); STG_A(3, 0, 0);

    int ktq = 0;
#pragma unroll 1
    for (int it = 0; it < 7; ++it) {
        TILE32(0, 65536, ktq + 8);  ktq += 8;
        TILE32(65536, 0, ktq + 8);  ktq += 8;
    }
    TILE32(0, 65536, 120);
    TILE32_LAST(65536);

    const int gc0 = vt * 256 + wc * 64 + l31;
#pragma unroll
    for (int p = 0; p < 4; ++p) {
#pragma unroll
        for (int j = 0; j < 2; ++j) {
            const int gcol = gc0 + j * 32;
#pragma unroll
            for (int r = 0; r < 16; ++r) {
                const int row = mt * 256 + p * 64 + wr * 32 + (r & 3) + 8 * (r >> 2) + 4 * h;
                out[((size_t)row * N_ + n) * V_ + gcol] = acc[p][j][r] + bias[j];
            }
        }
    }
}

// ---------------------------------------------------------------------------
extern "C" void kernel_launch(void* const* d_in, const int* in_sizes, int n_in,
                              void* d_out, int out_size, void* d_ws, size_t ws_size,
                              hipStream_t stream) {
    const float* ie  = (const float*)d_in[0];
    const int*   fts = (const int*)d_in[1];
    const float* emb = (const float*)d_in[2];
    const float* W   = (const float*)d_in[3];
    const float* bp  = (const float*)d_in[4];
    const float* gam = (const float*)d_in[5];
    const float* bet = (const float*)d_in[6];
    float* out = (float*)d_out;

    unsigned short* Wt = (unsigned short*)d_ws;                                     // 64 MiB (K-plane layout)
    unsigned short* H  = (unsigned short*)((char*)d_ws + (size_t)N_ * V_ * D_ * 2); // +32 MiB (K-plane layout)

    (void)hipFuncSetAttribute(reinterpret_cast<const void*>(gemm32),
                              hipFuncAttributeMaxDynamicSharedMemorySize, 131072);

    prep<<<dim3(2048 + 8192), dim3(256), 0, stream>>>(ie, fts, emb, gam, bet, W, H, Wt);
    gemm32<<<dim3(1024), dim3(512), 131072, stream>>>(H, Wt, bp, out);
}